// Round 2
// 562.746 us; speedup vs baseline: 1.0612x; 1.0612x over previous
//
#include <hip/hip_runtime.h>
#include <hip/hip_bf16.h>

#define ALPHA   0.3f
#define NEG_INF (-9e15f)
#define BN_EPS  1e-5f

typedef _Float16 f16x4 __attribute__((ext_vector_type(4)));
typedef _Float16 f16x8 __attribute__((ext_vector_type(8)));
typedef float    f32x4 __attribute__((ext_vector_type(4)));
typedef unsigned u32x4 __attribute__((ext_vector_type(4)));
typedef unsigned long long u64;

// ---------------------------------------------------------------------------
// K0: pack Wh[8,768,32] (f32) -> WcatT[256][768] (f16), WcatT[n][k] = Wcat[k,n]
// (B^T layout for the MFMA GEMM). 786KB read, ~2us.
// ---------------------------------------------------------------------------
__global__ __launch_bounds__(256) void k_wcat(const float* __restrict__ Wh,
                                              _Float16* __restrict__ WT)
{
    const int o = blockIdx.x * 256 + threadIdx.x;   // < 196608
    const int n = o / 768, k = o - n * 768;
    WT[o] = (_Float16)Wh[((n >> 5) * 768 + k) * 32 + (n & 31)];
}

// ---------------------------------------------------------------------------
// K0b (R6): pack adj>0 into bitmasks. Mw[row][4] u64, bit l of word t = col
// 64t+l. 41MB int32 -> 1.6MB (L2-resident). R6: Mw ALIASES the Y region
// (written by k_gemm2 only AFTER k_attn1 consumed Mw) so the workspace
// footprint stays at the proven 60,194,816 B -- R5 appended it past the end,
// the prime suspect for the container fault.
// ---------------------------------------------------------------------------
__global__ __launch_bounds__(256) void k_pack(const int* __restrict__ adj,
                                              u64* __restrict__ Mw)
{
    const int w = threadIdx.x >> 6, lane = threadIdx.x & 63;
    const int row = blockIdx.x * 4 + w;             // < 51200
    const int* ar = adj + (size_t)row * 200;
    #pragma unroll
    for (int t = 0; t < 4; ++t) {
        const int j = t * 64 + lane;
        const int a = ar[j < 200 ? j : 199];
        const u64 bal = __ballot(j < 200 && a > 0);
        if (lane == 0) Mw[(size_t)row * 4 + t] = bal;
    }
}

// ---------------------------------------------------------------------------
// K1: H[51200,256] = feat @ Wcat via f16 MFMA.
// R4: f32-VALU version was compute-bound (285us, VALUBusy=67%, MfmaUtil=0).
// Tile 64Mx256N, BK=64, 4 waves (each 64x64 = 4x4 16x16 tiles). feat converted
// f32->f16 inline into Af (rows padded 64->72 f16). M-only grid: feat read once.
// ---------------------------------------------------------------------------
__global__ __launch_bounds__(256) void k_gemm1(const float* __restrict__ A,
                                               const _Float16* __restrict__ WT,
                                               float* __restrict__ H)
{
    __shared__ _Float16 Af[64][72];    // [m][k]
    __shared__ _Float16 Bf[256][72];   // [n][k]
    const int tid  = threadIdx.x;
    const int wv   = tid >> 6;
    const int lane = tid & 63;
    const int r16  = lane & 15, q = lane >> 4;
    const size_t m_blk = (size_t)blockIdx.x * 64;
    const int wn = wv * 64;
    const int arow = tid >> 2, akb = (tid & 3) * 16;
    f32x4 acc[4][4] = {};   // [mi][ni]

    for (int kt = 0; kt < 768; kt += 64) {
        __syncthreads();
        #pragma unroll
        for (int p = 0; p < 4; ++p) {   // A: 64 rows x 64 k, f32 -> f16
            const float4 a4 = *(const float4*)&A[(m_blk + arow) * 768 + kt + akb + p * 4];
            f16x4 h4 = { (_Float16)a4.x, (_Float16)a4.y, (_Float16)a4.z, (_Float16)a4.w };
            *(f16x4*)&Af[arow][akb + p * 4] = h4;
        }
        #pragma unroll
        for (int p = 0; p < 8; ++p) {   // B: row n = tid, k 0..63 (f16 in global)
            f16x8 w8 = *(const f16x8*)&WT[tid * 768 + kt + p * 8];
            *(f16x8*)&Bf[tid][p * 8] = w8;
        }
        __syncthreads();
        #pragma unroll
        for (int kc = 0; kc < 64; kc += 32) {
            f16x8 af[4], bf[4];
            #pragma unroll
            for (int i = 0; i < 4; ++i)
                af[i] = *(const f16x8*)&Af[i * 16 + r16][kc + q * 8];
            #pragma unroll
            for (int j = 0; j < 4; ++j)
                bf[j] = *(const f16x8*)&Bf[wn + j * 16 + r16][kc + q * 8];
            #pragma unroll
            for (int i = 0; i < 4; ++i)
                #pragma unroll
                for (int j = 0; j < 4; ++j)
                    acc[i][j] = __builtin_amdgcn_mfma_f32_16x16x32_f16(
                        af[i], bf[j], acc[i][j], 0, 0, 0);
        }
    }
    #pragma unroll
    for (int i = 0; i < 4; ++i)
        #pragma unroll
        for (int j = 0; j < 4; ++j)
            #pragma unroll
            for (int r = 0; r < 4; ++r) {
                const int m = i * 16 + q * 4 + r;       // D row
                const int n = wn + j * 16 + r16;        // D col
                H[(m_blk + m) * 256 + n] = acc[i][j][r];
            }
}

// ---------------------------------------------------------------------------
// K2 (R5/R6 rewrite): per (b, head): s1/s2, masked softmax, out = att@H, elu,
// BN. Old: 160us, Occ=30%, VALUBusy=39%, MfmaUtil=1.5% -- latency-bound on 82M
// global adj loads + 10-hop shfl reduces + Pb LDS round-trip + 8-way HsT bank
// conflicts. New: wave owns a 16-row m-tile; lane owns P-row (lane&15) and
// j-slice (lane>>4)*8+32k == MFMA A-fragment layout, so P stays in registers
// (no Pb, no main-loop barriers). Row max/sum = 2 shfl_xor. Masks from
// L2-resident bitmasks staged in LDS. R6: pass-1 max is MASKED (cndmask per
// element) -- the unmasked-max shortcut could underflow all-f16 P rows when
// gap > ~17, a rare-row absmax blowup. HsT padded 224->232 f16 (116 words ==
// 20 mod 32): quarter-wave b128 reads hit every bank exactly 2x (free).
// LDS 25.2KB -> 6 blocks/CU. Scores still from f32 H (R3 lesson).
// ---------------------------------------------------------------------------
__global__ __launch_bounds__(256, 4) void k_attn1(float* __restrict__ H,
    const unsigned* __restrict__ Mw, const float* __restrict__ ah,
    const float* __restrict__ bng, const float* __restrict__ bnb,
    const float* __restrict__ bnm, const float* __restrict__ bnv)
{
    __shared__ alignas(16) _Float16 HsT[32][232];   // [f][j] B^T, stride 464B
    __shared__ alignas(16) unsigned Ml[208][8];     // row bitmask, word w = j in [32w,32w+32)
    __shared__ alignas(16) float s2[224];
    __shared__ float s1[208];
    __shared__ float av[64];
    __shared__ float bnA[208], bnB[208];
    const int tid  = threadIdx.x;
    const int b    = blockIdx.x >> 3;
    const int head = blockIdx.x & 7;
    float* Hb = H + (size_t)b * 200 * 256 + head * 32;
    const unsigned* Mb = Mw + (size_t)b * 200 * 8;

    // ---- phase A: stage H slice (f16, B^T), masks, av, fused BN coeffs ----
    for (int idx = tid; idx < 6400; idx += 256) {
        int n = idx >> 5, f = idx & 31;
        HsT[f][n] = (_Float16)Hb[n * 256 + f];
    }
    for (int idx = tid; idx < 32 * 32; idx += 256) {   // zero K-pad 200..231
        int f = idx >> 5, c = 200 + (idx & 31);
        HsT[f][c] = (_Float16)0.f;
    }
    for (int idx = tid; idx < 208 * 8; idx += 256) {
        int rr = idx >> 3, wd = idx & 7;
        Ml[rr][wd] = (rr < 200) ? Mb[rr * 8 + wd] : 0u;
    }
    if (tid < 64) av[tid] = ah[head * 64 + tid];
    if (tid < 208) {
        float iv = 0.f, cb = 0.f;
        if (tid < 200) {
            iv = bng[tid] * rsqrtf(bnv[tid] + BN_EPS);
            cb = bnb[tid] - bnm[tid] * iv;
        }
        bnA[tid] = iv; bnB[tid] = cb;
    }
    __syncthreads();

    // ---- phase B: s1/s2 from f32 global H (accuracy: R3 post-mortem) ----
    if (tid < 200) {
        float v1 = 0.f, v2 = 0.f;
        #pragma unroll
        for (int f = 0; f < 32; f += 4) {
            const float4 h4 = *(const float4*)&Hb[tid * 256 + f];
            v1 += h4.x * av[f]      + h4.y * av[f + 1]
                + h4.z * av[f + 2]  + h4.w * av[f + 3];
            v2 += h4.x * av[32 + f]     + h4.y * av[32 + f + 1]
                + h4.z * av[32 + f + 2] + h4.w * av[32 + f + 3];
        }
        s1[tid] = v1; s2[tid] = v2;
    } else {
        if (tid < 208) s1[tid] = 0.f;
        if (tid < 224) s2[tid] = 0.f;   // finite pad: mask bits are 0 there
    }
    __syncthreads();

    const int lane = tid & 63, wv = tid >> 6;
    const int r16 = lane & 15, q = lane >> 4;

    for (int tile = wv; tile < 13; tile += 4) {      // 13 m-tiles, round robin
        const int m0  = tile * 16;
        const int row = m0 + r16;                    // this lane's P-row
        const float s1i = s1[row];
        const u32x4 mwa = *(const u32x4*)&Ml[row][0];
        const u32x4 mwb = *(const u32x4*)&Ml[row][4];
        const unsigned mw[7] = {mwa[0], mwa[1], mwa[2], mwa[3],
                                mwb[0], mwb[1], mwb[2]};

        // pass 1: masked row max (R6: no unmasked-max underflow tail risk)
        float m = -INFINITY;
        #pragma unroll
        for (int ks = 0; ks < 7; ++ks) {
            const f32x4 sA = *(const f32x4*)&s2[ks * 32 + q * 8];
            const f32x4 sB = *(const f32x4*)&s2[ks * 32 + q * 8 + 4];
            const unsigned wb = mw[ks] >> (q * 8);
            #pragma unroll
            for (int e = 0; e < 8; ++e) {
                const float sv = (e < 4) ? sA[e] : sB[e - 4];
                const float t = s1i + sv;
                const float tl = fmaxf(t, ALPHA * t);   // leaky via max (a<1)
                m = fmaxf(m, ((wb >> e) & 1u) ? tl : -INFINITY);
            }
        }
        m = fmaxf(m, __shfl_xor(m, 16));
        m = fmaxf(m, __shfl_xor(m, 32));

        // pass 2: p = mask ? exp(e-m) : 0, packed straight into A-fragments
        float s = 0.f;
        f16x8 pa[7];
        #pragma unroll
        for (int ks = 0; ks < 7; ++ks) {
            const f32x4 sA = *(const f32x4*)&s2[ks * 32 + q * 8];
            const f32x4 sB = *(const f32x4*)&s2[ks * 32 + q * 8 + 4];
            const unsigned wb = mw[ks] >> (q * 8);
            #pragma unroll
            for (int e = 0; e < 8; ++e) {
                const float sv = (e < 4) ? sA[e] : sB[e - 4];
                float t = s1i + sv;
                t = fmaxf(t, ALPHA * t);
                float pe = __expf(t - m);            // <= 1: f16-safe
                pe = ((wb >> e) & 1u) ? pe : 0.f;
                s += pe;
                pa[ks][e] = (_Float16)pe;
            }
        }
        s += __shfl_xor(s, 16);
        s += __shfl_xor(s, 32);
        const float sinv = 1.f / s;

        // O[16,32] = P @ H : 2 f-tiles, A from registers, B from padded HsT
        f32x4 acc0 = {0.f, 0.f, 0.f, 0.f}, acc1 = {0.f, 0.f, 0.f, 0.f};
        #pragma unroll
        for (int ks = 0; ks < 7; ++ks) {
            const int k0 = ks * 32 + q * 8;
            const f16x8 b0 = *(const f16x8*)&HsT[r16][k0];
            const f16x8 b1 = *(const f16x8*)&HsT[16 + r16][k0];
            acc0 = __builtin_amdgcn_mfma_f32_16x16x32_f16(pa[ks], b0, acc0, 0, 0, 0);
            acc1 = __builtin_amdgcn_mfma_f32_16x16x32_f16(pa[ks], b1, acc1, 0, 0, 0);
        }
        // D layout: row = q*4+r, col = r16. sinv for row i lives at lane i&15.
        float rv[4];
        #pragma unroll
        for (int r = 0; r < 4; ++r) rv[r] = __shfl(sinv, q * 4 + r);
        #pragma unroll
        for (int r = 0; r < 4; ++r) {
            const int i = m0 + q * 4 + r;
            if (i < 200) {
                float o0 = acc0[r] * rv[r];
                float o1 = acc1[r] * rv[r];
                o0 = o0 > 0.f ? o0 : expm1f(o0);     // elu
                o1 = o1 > 0.f ? o1 : expm1f(o1);
                const float ga = bnA[i], gb = bnB[i];
                Hb[i * 256 + r16]      = o0 * ga + gb;
                Hb[i * 256 + 16 + r16] = o1 * ga + gb;
            }
        }
    }
}

// ---------------------------------------------------------------------------
// K3: Y[51200,36] = x[51200,256] @ [W_sent | W_para | W_qt]
// Col group g (9 cols) lives at 16B-aligned 12-float slot in LDS; inner loop
// kept at unroll-4 to stop LLVM from fully unrolling and spilling (round-1
// pathology: VGPR=256, 1.9 GB scratch traffic, 1530 us).
// ---------------------------------------------------------------------------
__global__ __launch_bounds__(256) void k_gemm2(const float* __restrict__ X,
    const float* __restrict__ Ws, const float* __restrict__ Wp,
    const float* __restrict__ Wq, float* __restrict__ Y)
{
    __shared__ float Wl[256][48];   // [k][12*g + c], c<9 used, pads never read
    __shared__ float XsT[64][68];   // [k][row]
    const int tid = threadIdx.x;
    {   // stage weights (once): thread tid = row k
        const int k = tid;
        #pragma unroll
        for (int c = 0; c < 36; ++c) {
            float v;
            if      (c == 0) v = Ws[k * 2 + 0];
            else if (c == 1) v = Ws[k * 2 + 1];
            else if (c == 2) v = Wp[k * 2 + 0];
            else if (c == 3) v = Wp[k * 2 + 1];
            else             v = Wq[k * 32 + (c - 4)];
            Wl[k][12 * (c / 9) + (c % 9)] = v;
        }
    }
    const int r  = tid & 63;        // row within tile (wave-contiguous)
    const int cg = tid >> 6;        // col group 0..3 (uniform per wave)
    const size_t row0 = (size_t)blockIdx.x * 64;
    float acc[9] = {};

    for (int kt = 0; kt < 256; kt += 64) {
        __syncthreads();
        #pragma unroll
        for (int i = 0; i < 4; ++i) {      // 64x64 X tile, transposed into LDS
            int l = tid + 256 * i;
            int row = l >> 4;
            int k4 = (l & 15) * 4;
            const float4 x4 = *(const float4*)&X[(row0 + row) * 256 + kt + k4];
            XsT[k4 + 0][row] = x4.x; XsT[k4 + 1][row] = x4.y;
            XsT[k4 + 2][row] = x4.z; XsT[k4 + 3][row] = x4.w;
        }
        __syncthreads();
        #pragma unroll 4
        for (int k = 0; k < 64; ++k) {
            const float xv = XsT[k][r];
            const float4 w0 = *(const float4*)&Wl[kt + k][12 * cg + 0];
            const float4 w1 = *(const float4*)&Wl[kt + k][12 * cg + 4];
            const float  w2 = Wl[kt + k][12 * cg + 8];
            acc[0] += xv * w0.x; acc[1] += xv * w0.y;
            acc[2] += xv * w0.z; acc[3] += xv * w0.w;
            acc[4] += xv * w1.x; acc[5] += xv * w1.y;
            acc[6] += xv * w1.z; acc[7] += xv * w1.w;
            acc[8] += xv * w2;
        }
    }
    float* yr = Y + (row0 + r) * 36 + cg * 9;
    #pragma unroll
    for (int c = 0; c < 9; ++c) yr[c] = acc[c];
}

// ---------------------------------------------------------------------------
// K4 (R6): 2nd-layer attention, proven R4 logic (direct adj loads -- Mw is
// gone by now, its region was overwritten by k_gemm2). Grid 256->512: half
// the rows per block (old was 1 block/CU = 12.5% occupancy).
// ---------------------------------------------------------------------------
__global__ __launch_bounds__(256) void k_attn2(const float* __restrict__ Y,
    const int* __restrict__ adj, const float* __restrict__ a_s,
    const float* __restrict__ a_p, const float* __restrict__ a_q,
    const float* __restrict__ W2, float* __restrict__ out)
{
    __shared__ float Ys[200][37];
    __shared__ float s1s[200], s2s[200], p1s[200], p2s[200], sq2[200];
    __shared__ float p0[200];
    __shared__ float hqt[32];
    __shared__ float sumq_s;
    __shared__ float asl[4], apl[4], aql[64], w2l[64];
    const int tid  = threadIdx.x;
    const int b    = blockIdx.x >> 1;
    const int half = blockIdx.x & 1;
    const float* Yb = Y + (size_t)b * 7200;
    const int* adjb = adj + (size_t)b * 200 * 200;

    for (int idx = tid; idx < 7200; idx += 256) {
        int j = idx / 36;
        int c = idx - j * 36;
        Ys[j][c] = Yb[idx];
    }
    if (tid < 4)  { asl[tid] = a_s[tid]; apl[tid] = a_p[tid]; }
    if (tid < 64) { aql[tid] = a_q[tid]; w2l[tid] = W2[tid]; }
    __syncthreads();

    if (tid < 200) {
        int j = tid;
        s1s[j] = Ys[j][0] * asl[0] + Ys[j][1] * asl[1];
        s2s[j] = Ys[j][0] * asl[2] + Ys[j][1] * asl[3];
        p1s[j] = Ys[j][2] * apl[0] + Ys[j][3] * apl[1];
        p2s[j] = Ys[j][2] * apl[2] + Ys[j][3] * apl[3];
        float a = 0.f;
        #pragma unroll
        for (int f = 0; f < 32; ++f) a += Ys[j][4 + f] * aql[32 + f];
        sq2[j] = a;
    }
    __syncthreads();

    const int w = tid >> 6, lane = tid & 63;
    for (int ii = w; ii < 100; ii += 4) {   // one wave per row, half the rows
        const int i = half * 100 + ii;
        const float s1i = s1s[i], p1i = p1s[i];
        float ms = -INFINITY, mp = -INFINITY;
        float es[4], ep[4];
        #pragma unroll
        for (int t = 0; t < 4; ++t) {
            int j = lane + 64 * t;
            int jj = j < 200 ? j : 0;
            int a = (j < 200) ? adjb[i * 200 + j] : 0;
            float e1 = s1i + s2s[jj]; e1 = e1 >= 0.f ? e1 : ALPHA * e1;
            float e2 = p1i + p2s[jj]; e2 = e2 >= 0.f ? e2 : ALPHA * e2;
            es[t] = (a > 0) ? e1 : (j < 200 ? NEG_INF : -INFINITY);
            ep[t] = (a > 0) ? e2 : (j < 200 ? NEG_INF : -INFINITY);
            ms = fmaxf(ms, es[t]); mp = fmaxf(mp, ep[t]);
        }
        #pragma unroll
        for (int off = 32; off >= 1; off >>= 1) {
            ms = fmaxf(ms, __shfl_xor(ms, off));
            mp = fmaxf(mp, __shfl_xor(mp, off));
        }
        float ss = 0.f, sp = 0.f, os0 = 0.f, os1 = 0.f, op0 = 0.f, op1 = 0.f;
        #pragma unroll
        for (int t = 0; t < 4; ++t) {
            int j = lane + 64 * t;
            int jj = j < 200 ? j : 0;
            float pes = __expf(es[t] - ms);
            float pep = __expf(ep[t] - mp);
            ss += pes; sp += pep;
            os0 += pes * Ys[jj][0]; os1 += pes * Ys[jj][1];
            op0 += pep * Ys[jj][2]; op1 += pep * Ys[jj][3];
        }
        #pragma unroll
        for (int off = 32; off >= 1; off >>= 1) {
            ss  += __shfl_xor(ss, off);  sp  += __shfl_xor(sp, off);
            os0 += __shfl_xor(os0, off); os1 += __shfl_xor(os1, off);
            op0 += __shfl_xor(op0, off); op1 += __shfl_xor(op1, off);
        }
        if (lane == 0) {
            float v0 = os0 / ss, v1 = os1 / ss;
            out[((size_t)b * 200 + i) * 2 + 0] = 1.f / (1.f + __expf(-v0));
            out[((size_t)b * 200 + i) * 2 + 1] = 1.f / (1.f + __expf(-v1));
            float q0 = op0 / sp, q1 = op1 / sp;
            out[102400 + ((size_t)b * 200 + i) * 2 + 0] = q0 > 0.f ? q0 : expm1f(q0);
            out[102400 + ((size_t)b * 200 + i) * 2 + 1] = q1 > 0.f ? q1 : expm1f(q1);
        }
    }

    // ---- qtype head: attention row 0 only (half 0 blocks) ----
    if (half == 0 && tid < 64) {
        float s1q = 0.f;
        #pragma unroll
        for (int f = 0; f < 32; ++f) s1q += Ys[0][4 + f] * aql[f];
        float mq = -INFINITY;
        float eq[4];
        #pragma unroll
        for (int t = 0; t < 4; ++t) {
            int j = tid + 64 * t;
            int jj = j < 200 ? j : 0;
            int a = (j < 200) ? adjb[j] : 0;
            float e = s1q + sq2[jj]; e = e >= 0.f ? e : ALPHA * e;
            eq[t] = (a > 0) ? e : (j < 200 ? NEG_INF : -INFINITY);
            mq = fmaxf(mq, eq[t]);
        }
        #pragma unroll
        for (int off = 32; off >= 1; off >>= 1) mq = fmaxf(mq, __shfl_xor(mq, off));
        float sq = 0.f;
        #pragma unroll
        for (int t = 0; t < 4; ++t) {
            int j = tid + 64 * t;
            float pe = __expf(eq[t] - mq);
            sq += pe;
            if (j < 200) p0[j] = pe;
        }
        #pragma unroll
        for (int off = 32; off >= 1; off >>= 1) sq += __shfl_xor(sq, off);
        if (tid == 0) sumq_s = sq;
    }
    __syncthreads();
    if (half == 0 && tid < 32) {
        float acc = 0.f;
        for (int j = 0; j < 200; ++j) acc += p0[j] * Ys[j][4 + tid];
        hqt[tid] = acc / sumq_s;
    }
    __syncthreads();
    if (half == 0 && tid < 2) {
        float v = 0.f;
        #pragma unroll
        for (int f = 0; f < 32; ++f) v += hqt[f] * w2l[f * 2 + tid];
        out[204800 + (size_t)b * 2 + tid] = v > 0.f ? v : expm1f(v);
    }
}

// ---------------------------------------------------------------------------
extern "C" void kernel_launch(void* const* d_in, const int* in_sizes, int n_in,
                              void* d_out, int out_size, void* d_ws, size_t ws_size,
                              hipStream_t stream) {
    const float* feat   = (const float*)d_in[0];   // [256,200,768]
    const int*   adj    = (const int*)  d_in[1];   // [256,200,200]
    const float* Wh     = (const float*)d_in[2];   // [8,768,32]
    const float* ah     = (const float*)d_in[3];   // [8,64,1]
    const float* W_sent = (const float*)d_in[4];   // [256,2]
    const float* a_sent = (const float*)d_in[5];   // [4,1]
    const float* W_para = (const float*)d_in[6];   // [256,2]
    const float* a_para = (const float*)d_in[7];   // [4,1]
    const float* W_qt   = (const float*)d_in[8];   // [256,32]
    const float* a_qt   = (const float*)d_in[9];   // [64,1]
    const float* W2     = (const float*)d_in[10];  // [32,2]
    const float* bng    = (const float*)d_in[11];
    const float* bnb    = (const float*)d_in[12];
    const float* bnm    = (const float*)d_in[13];
    const float* bnv    = (const float*)d_in[14];

    float* H = (float*)d_ws;                 // [51200,256] -> becomes x in place
    float* Y = H + (size_t)51200 * 256;      // [51200,36]
    _Float16* WT = (_Float16*)(Y + (size_t)51200 * 36);  // [256,768] f16
    // Mw [51200][4] u64 = 1.6MB ALIASES Y (live only between k_pack and
    // k_attn1; k_gemm2 overwrites it afterwards). Footprint unchanged.
    u64* Mw = (u64*)Y;
    float* out = (float*)d_out;

    k_wcat<<<768, 256, 0, stream>>>(Wh, WT);
    k_pack<<<12800, 256, 0, stream>>>(adj, Mw);
    k_gemm1<<<800, 256, 0, stream>>>(feat, WT, H);
    k_attn1<<<2048, 256, 0, stream>>>(H, (const unsigned*)Mw, ah, bng, bnb, bnm, bnv);
    k_gemm2<<<800, 256, 0, stream>>>(H, W_sent, W_para, W_qt, Y);
    k_attn2<<<512, 256, 0, stream>>>(Y, adj, a_sent, a_para, a_qt, W2, out);
}